// Round 10
// baseline (172.108 us; speedup 1.0000x reference)
//
#include <hip/hip_runtime.h>
#include <math.h>

namespace {

typedef __attribute__((ext_vector_type(8))) __fp16 f16x8;
typedef __attribute__((ext_vector_type(4))) float f32x4;

constexpr int IN_DIM = 128;
constexpr int EFF    = 130 * 16;   // W1 node stride (floats)
constexpr int NODES  = 255;
constexpr int TS     = 32;         // samples per block (2 MFMA N-tiles per wave)
constexpr int BLOCK  = 256;
constexpr int NC     = 10;

// ---- prep: W1[:, :128, :] -> MFMA fragment layout, fp16 (single product) ----
// frag element (n, t, lane l, j): W[k = t*32 + (l>>4)*8 + j][hid = l&15]
__global__ __launch_bounds__(256) void prep_w1(const float* __restrict__ W1,
                                               f16x8* __restrict__ wfrag) {
    __shared__ float xs[IN_DIM * 16];      // 8 KB: rows 0..127 of this node
    const int n = blockIdx.x, tid = threadIdx.x;
    const float4* src = (const float4*)(W1 + (size_t)n * EFF);
    ((float4*)xs)[tid]       = src[tid];
    ((float4*)xs)[tid + 256] = src[tid + 256];
    __syncthreads();
    const int l = tid & 63, t = tid >> 6;
    const int k0 = t * 32 + (l >> 4) * 8, hid = l & 15;
    f16x8 hv;
    #pragma unroll
    for (int j = 0; j < 8; ++j)
        hv[j] = (__fp16)xs[(k0 + j) * 16 + hid];   // RNE
    wfrag[(n * 4 + t) * 64 + l] = hv;
}

// ---- main fused tree kernel ----
// R10: TS=32 -> 1024 blocks, 4 blocks/CU (30 KB LDS), 4 waves/SIMD for
// latency overlap; whole-node W prefetch (wnext[4]) issued one full
// iteration ahead. fp16 single-product arithmetic identical to R9.
__global__ __launch_bounds__(BLOCK) __attribute__((amdgpu_waves_per_eu(4, 4)))
void tree_mfma(
    const float* __restrict__ x, const float* __restrict__ path_prob,
    const float* __restrict__ W1, const float* __restrict__ b1,
    const float* __restrict__ w2, const float* __restrict__ b2,
    const float* __restrict__ leaf_logits,
    const f16x8* __restrict__ wfrag,
    float* __restrict__ out)
{
    __shared__ float pp[128][TS];          // 16 KB: path probs, depths 0..6 only
    // rotating score buffers: buf0 (d=0,3,6): 64 rows @0; buf1 (d=1,4): 16 @64; buf2 (d=2,5): 32 @80
    __shared__ float scbuf[112][TS];       // 14 KB (reused for out-reduction)

    const int tid  = threadIdx.x;
    const int wv   = tid >> 6, l = tid & 63;
    const int quad = l >> 4,   col = l & 15;
    const int lo32 = l & 31;
    const int s0   = blockIdx.x * TS;

    if (tid < TS) pp[0][tid] = path_prob[s0 + tid];

    // x fragments (fp16): B operand B[k = t*32+quad*8+j][col = sample&15]
    f16x8 xh[4][2];
    #pragma unroll
    for (int t = 0; t < 4; ++t)
        #pragma unroll
        for (int mt = 0; mt < 2; ++mt) {
            const float* xp = x + (size_t)(s0 + mt * 16 + col) * IN_DIM + t * 32 + quad * 8;
            float4 v0 = ((const float4*)xp)[0];
            float4 v1 = ((const float4*)xp)[1];
            float vv[8] = {v0.x, v0.y, v0.z, v0.w, v1.x, v1.y, v1.z, v1.w};
            f16x8 hv;
            #pragma unroll
            for (int j = 0; j < 8; ++j) hv[j] = (__fp16)vv[j];
            xh[t][mt] = hv;
        }
    // no barrier needed: first cross-wave LDS reads are behind the d0->d1 barrier

    const int wbase[3] = {0, 64, 80};

    // peel: preload first node's full W (per-wave first node: {0,2,5,6})
    const int first_n = (wv == 0) ? 0 : (wv == 1) ? 2 : (wv == 2) ? 5 : 6;
    f16x8 wcur[4];
    #pragma unroll
    for (int t = 0; t < 4; ++t) wcur[t] = wfrag[(size_t)first_n * 256 + t * 64 + l];

    // ---------------- depths 0..6 ----------------
    for (int d = 0; d < 7; ++d) {
        const int nd = 1 << d;
        float (*scW)[TS]  = (float(*)[TS])&scbuf[wbase[d % 3]][0];
        float (*scP)[TS]  = (float(*)[TS])&scbuf[wbase[(d + 2) % 3]][0];   // d-1
        float (*scP2)[TS] = (float(*)[TS])&scbuf[wbase[(d + 1) % 3]][0];   // d-2
        const int stride = 128 >> d, half = 64 >> d;

        for (int nl = wv; nl < nd; nl += 4) {
            const int n = nd - 1 + nl;
            // successor node in this wave's global sequence (crosses depth bound)
            const int nn = (nl + 4 < nd) ? (n + 4) : (2 * nd - 1 + wv);

            // ---- prefetch next node's full W: consumed NEXT iter (~450+ cyc cover) ----
            f16x8 wnext[4];
            {
                const f16x8* wnp = wfrag + (size_t)nn * 256 + l;
                #pragma unroll
                for (int t = 0; t < 4; ++t) wnext[t] = wnp[t * 64];
            }

            // ---- hoisted epilogue operands ----
            const float4 b1q = ((const float4*)(b1 + n * 16))[quad];
            const float4 w2q = ((const float4*)(w2 + n * 16))[quad];
            const float4 wpq = ((const float4*)(W1 + (size_t)n * EFF + 128 * 16))[quad];
            const float4 wgq = ((const float4*)(W1 + (size_t)n * EFF + 129 * 16))[quad];
            const float  b2v = b2[n];
            const int    slot = nl * stride;
            const float  ppar = pp[slot][lo32];
            float par[2], gp[2];
            #pragma unroll
            for (int mt = 0; mt < 2; ++mt) {
                const int scol = mt * 16 + col;
                par[mt] = (d >= 1) ? scP[nl >> 1][scol] : 0.0f;
                gp[mt]  = (d >= 2) ? scP2[nl >> 2][scol] : 0.0f;
            }

            // ---- MFMA t-loop: all operands already in registers ----
            f32x4 binit = {b1q.x, b1q.y, b1q.z, b1q.w};
            f32x4 acc[2] = {binit, binit};
            #pragma unroll
            for (int t = 0; t < 4; ++t) {
                acc[0] = __builtin_amdgcn_mfma_f32_16x16x32_f16(wcur[t], xh[t][0], acc[0], 0, 0, 0);
                acc[1] = __builtin_amdgcn_mfma_f32_16x16x32_f16(wcur[t], xh[t][1], acc[1], 0, 0, 0);
            }

            // epilogue: D[hid=quad*4+r][s=mt*16+col]; hid-reduce = 3 adds + 2 shfls
            float score01[2];
            #pragma unroll
            for (int mt = 0; mt < 2; ++mt) {
                const f32x4 a = acc[mt];
                const float pa = par[mt], ga = gp[mt];
                float ts = 0.0f;
                #pragma unroll
                for (int r = 0; r < 4; ++r) {
                    const float wpr = (r == 0) ? wpq.x : (r == 1) ? wpq.y : (r == 2) ? wpq.z : wpq.w;
                    const float wgr = (r == 0) ? wgq.x : (r == 1) ? wgq.y : (r == 2) ? wgq.z : wgq.w;
                    const float w2r = (r == 0) ? w2q.x : (r == 1) ? w2q.y : (r == 2) ? w2q.z : w2q.w;
                    const float h = fmaf(pa, wpr, fmaf(ga, wgr, a[r]));
                    ts = fmaf(fmaxf(h, 0.0f), w2r, ts);
                }
                ts += __shfl_xor(ts, 16);
                ts += __shfl_xor(ts, 32);
                score01[mt] = ts;
            }
            // lane l owns sample lo32 (both half-waves hold identical reduced scores)
            const float sv = ((l & 16) ? score01[1] : score01[0]) + b2v;

            if (l < 32) {
                scW[nl][lo32] = sv;
                const float p = 1.0f / (1.0f + __expf(-sv));
                pp[slot][lo32]        = ppar * p;
                pp[slot + half][lo32] = ppar * (1.0f - p);
            }

            #pragma unroll
            for (int t = 0; t < 4; ++t) wcur[t] = wnext[t];
        }
        __syncthreads();
    }

    // ---------------- depth 7: fold leaf mixture, accumulate in VGPRs ----------------
    float oacc[NC];
    #pragma unroll
    for (int c = 0; c < NC; ++c) oacc[c] = 0.0f;
    {
        float (*scP)[TS]  = (float(*)[TS])&scbuf[wbase[0]][0];   // d=6 scores
        float (*scP2)[TS] = (float(*)[TS])&scbuf[wbase[2]][0];   // d=5 scores

        for (int nl = wv; nl < 128; nl += 4) {
            const int n = 127 + nl;
            const int nn = (nl + 4 < 128) ? (n + 4) : 254;   // dummy refetch at end

            f16x8 wnext[4];
            {
                const f16x8* wnp = wfrag + (size_t)nn * 256 + l;
                #pragma unroll
                for (int t = 0; t < 4; ++t) wnext[t] = wnp[t * 64];
            }

            const float4 b1q = ((const float4*)(b1 + n * 16))[quad];
            const float4 w2q = ((const float4*)(w2 + n * 16))[quad];
            const float4 wpq = ((const float4*)(W1 + (size_t)n * EFF + 128 * 16))[quad];
            const float4 wgq = ((const float4*)(W1 + (size_t)n * EFF + 129 * 16))[quad];
            const float  b2v = b2[n];
            const float  ppar = pp[nl][lo32];
            float par[2], gp[2];
            #pragma unroll
            for (int mt = 0; mt < 2; ++mt) {
                const int scol = mt * 16 + col;
                par[mt] = scP[nl >> 1][scol];
                gp[mt]  = scP2[nl >> 2][scol];
            }

            f32x4 binit = {b1q.x, b1q.y, b1q.z, b1q.w};
            f32x4 acc[2] = {binit, binit};
            #pragma unroll
            for (int t = 0; t < 4; ++t) {
                acc[0] = __builtin_amdgcn_mfma_f32_16x16x32_f16(wcur[t], xh[t][0], acc[0], 0, 0, 0);
                acc[1] = __builtin_amdgcn_mfma_f32_16x16x32_f16(wcur[t], xh[t][1], acc[1], 0, 0, 0);
            }

            float score01[2];
            #pragma unroll
            for (int mt = 0; mt < 2; ++mt) {
                const f32x4 a = acc[mt];
                const float pa = par[mt], ga = gp[mt];
                float ts = 0.0f;
                #pragma unroll
                for (int r = 0; r < 4; ++r) {
                    const float wpr = (r == 0) ? wpq.x : (r == 1) ? wpq.y : (r == 2) ? wpq.z : wpq.w;
                    const float wgr = (r == 0) ? wgq.x : (r == 1) ? wgq.y : (r == 2) ? wgq.z : wgq.w;
                    const float w2r = (r == 0) ? w2q.x : (r == 1) ? w2q.y : (r == 2) ? w2q.z : w2q.w;
                    const float h = fmaf(pa, wpr, fmaf(ga, wgr, a[r]));
                    ts = fmaf(fmaxf(h, 0.0f), w2r, ts);
                }
                ts += __shfl_xor(ts, 16);
                ts += __shfl_xor(ts, 32);
                score01[mt] = ts;
            }
            const float sv = ((l & 16) ? score01[1] : score01[0]) + b2v;

            const float p = 1.0f / (1.0f + __expf(-sv));
            const float pL = ppar * p;
            const float pR = ppar * (1.0f - p);
            const float* llp = leaf_logits + (size_t)(2 * nl) * NC;
            #pragma unroll
            for (int c = 0; c < NC; ++c)
                oacc[c] = fmaf(pL, llp[c], fmaf(pR, llp[NC + c], oacc[c]));

            #pragma unroll
            for (int t = 0; t < 4; ++t) wcur[t] = wnext[t];
        }
    }

    // ---------------- cross-wave out reduction through scbuf ----------------
    __syncthreads();
    {
        float* red = &scbuf[0][0];         // 4*32*10 = 1280 floats <= 3584
        if (l < 32) {
            #pragma unroll
            for (int c = 0; c < NC; ++c)
                red[(wv * 32 + lo32) * NC + c] = oacc[c];
        }
    }
    __syncthreads();
    {
        const float* red = &scbuf[0][0];
        for (int i = tid; i < TS * NC; i += BLOCK) {
            float v = red[i] + red[320 + i] + red[640 + i] + red[960 + i];
            out[(size_t)s0 * NC + i] = v;
        }
    }
}

} // namespace

extern "C" void kernel_launch(void* const* d_in, const int* in_sizes, int n_in,
                              void* d_out, int out_size, void* d_ws, size_t ws_size,
                              hipStream_t stream) {
    const float* x           = (const float*)d_in[0];
    const float* path_prob   = (const float*)d_in[1];
    const float* W1          = (const float*)d_in[2];
    const float* b1          = (const float*)d_in[3];
    const float* w2          = (const float*)d_in[4];
    const float* b2          = (const float*)d_in[5];
    const float* leaf_logits = (const float*)d_in[6];
    float* out = (float*)d_out;

    const int batch = in_sizes[0] / IN_DIM;                // 32768
    f16x8* wfrag = (f16x8*)d_ws;                           // 255*4*64*16B ~= 1.04 MB

    hipLaunchKernelGGL(prep_w1, dim3(NODES), dim3(256), 0, stream, W1, wfrag);
    hipLaunchKernelGGL(tree_mfma, dim3(batch / TS), dim3(BLOCK), 0, stream,
                       x, path_prob, W1, b1, w2, b2, leaf_logits, wfrag, out);
}

// Round 11
// 150.473 us; speedup vs baseline: 1.1438x; 1.1438x over previous
//
#include <hip/hip_runtime.h>
#include <math.h>

namespace {

typedef __attribute__((ext_vector_type(8))) __fp16 f16x8;
typedef __attribute__((ext_vector_type(4))) float f32x4;

constexpr int IN_DIM = 128;
constexpr int EFF    = 130 * 16;   // W1 node stride (floats)
constexpr int NODES  = 255;
constexpr int TS     = 64;         // samples per block (4 MFMA N-tiles per wave)
constexpr int BLOCK  = 256;
constexpr int NC     = 10;

// ---- prep: W1[:, :128, :] -> MFMA fragment layout, fp16 (single product) ----
// frag element (n, t, lane l, j): W[k = t*32 + (l>>4)*8 + j][hid = l&15]
__global__ __launch_bounds__(256) void prep_w1(const float* __restrict__ W1,
                                               f16x8* __restrict__ wfrag) {
    __shared__ float xs[IN_DIM * 16];      // 8 KB: rows 0..127 of this node
    const int n = blockIdx.x, tid = threadIdx.x;
    const float4* src = (const float4*)(W1 + (size_t)n * EFF);
    ((float4*)xs)[tid]       = src[tid];
    ((float4*)xs)[tid + 256] = src[tid + 256];
    __syncthreads();
    const int l = tid & 63, t = tid >> 6;
    const int k0 = t * 32 + (l >> 4) * 8, hid = l & 15;
    f16x8 hv;
    #pragma unroll
    for (int j = 0; j < 8; ++j)
        hv[j] = (__fp16)xs[(k0 + j) * 16 + hid];   // RNE
    wfrag[(n * 4 + t) * 64 + l] = hv;
}

// ---- main fused tree kernel ----
// R11 = R9 (TS=64, waves_per_eu(2,2): arch-VGPR cap 128, proven spill-free)
// + R10's whole-node W prefetch: wnext[4] issued at iter start, consumed
// one full iteration (~700+ cyc) later -> no exposed L2 latency.
// R10 lesson: waves_per_eu(4,4) halves the arch-VGPR cap to 64 -> spills.
__global__ __launch_bounds__(BLOCK) __attribute__((amdgpu_waves_per_eu(2, 2)))
void tree_mfma(
    const float* __restrict__ x, const float* __restrict__ path_prob,
    const float* __restrict__ W1, const float* __restrict__ b1,
    const float* __restrict__ w2, const float* __restrict__ b2,
    const float* __restrict__ leaf_logits,
    const f16x8* __restrict__ wfrag,
    float* __restrict__ out)
{
    __shared__ float pp[128][TS];          // 32 KB: path probs, depths 0..6 only
    // rotating score buffers: buf0 (d=0,3,6): 64 rows @0; buf1 (d=1,4): 16 @64; buf2 (d=2,5): 32 @80
    __shared__ float scbuf[112][TS];       // 28 KB (reused for out-reduction)

    const int tid  = threadIdx.x;
    const int wv   = tid >> 6, l = tid & 63;
    const int quad = l >> 4,   col = l & 15;
    const int s0   = blockIdx.x * TS;

    if (tid < TS) pp[0][tid] = path_prob[s0 + tid];

    // x fragments (fp16): B operand B[k = t*32+quad*8+j][col]
    f16x8 xh[4][4];
    #pragma unroll
    for (int t = 0; t < 4; ++t)
        #pragma unroll
        for (int mt = 0; mt < 4; ++mt) {
            const float* xp = x + (size_t)(s0 + mt * 16 + col) * IN_DIM + t * 32 + quad * 8;
            float4 v0 = ((const float4*)xp)[0];
            float4 v1 = ((const float4*)xp)[1];
            float vv[8] = {v0.x, v0.y, v0.z, v0.w, v1.x, v1.y, v1.z, v1.w};
            f16x8 hv;
            #pragma unroll
            for (int j = 0; j < 8; ++j) hv[j] = (__fp16)vv[j];
            xh[t][mt] = hv;
        }

    const int wbase[3] = {0, 64, 80};

    // peel: preload first node's full W (per-wave first node: {0,2,5,6})
    const int first_n = (wv == 0) ? 0 : (wv == 1) ? 2 : (wv == 2) ? 5 : 6;
    f16x8 wcur[4];
    #pragma unroll
    for (int t = 0; t < 4; ++t) wcur[t] = wfrag[(size_t)first_n * 256 + t * 64 + l];

    // ---------------- depths 0..6 ----------------
    for (int d = 0; d < 7; ++d) {
        const int nd = 1 << d;
        float (*scW)[TS]  = (float(*)[TS])&scbuf[wbase[d % 3]][0];
        float (*scP)[TS]  = (float(*)[TS])&scbuf[wbase[(d + 2) % 3]][0];   // d-1
        float (*scP2)[TS] = (float(*)[TS])&scbuf[wbase[(d + 1) % 3]][0];   // d-2
        const int stride = 128 >> d, half = 64 >> d;

        for (int nl = wv; nl < nd; nl += 4) {
            const int n = nd - 1 + nl;
            // successor node in this wave's global sequence (crosses depth bound)
            const int nn = (nl + 4 < nd) ? (n + 4) : (2 * nd - 1 + wv);

            // ---- full next-node W prefetch: consumed NEXT iteration ----
            f16x8 wnext[4];
            {
                const f16x8* wnp = wfrag + (size_t)nn * 256 + l;
                #pragma unroll
                for (int t = 0; t < 4; ++t) wnext[t] = wnp[t * 64];
            }

            // ---- hoisted epilogue operands (hidden under the MFMA block) ----
            const float4 b1q = ((const float4*)(b1 + n * 16))[quad];
            const float4 w2q = ((const float4*)(w2 + n * 16))[quad];
            const float4 wpq = ((const float4*)(W1 + (size_t)n * EFF + 128 * 16))[quad];
            const float4 wgq = ((const float4*)(W1 + (size_t)n * EFF + 129 * 16))[quad];
            const float  b2v = b2[n];
            const int    slot = nl * stride;
            const float  ppar = pp[slot][l];
            float par[4], gp[4];
            #pragma unroll
            for (int mt = 0; mt < 4; ++mt) {
                const int scol = mt * 16 + col;
                par[mt] = (d >= 1) ? scP[nl >> 1][scol] : 0.0f;
                gp[mt]  = (d >= 2) ? scP2[nl >> 2][scol] : 0.0f;
            }

            // ---- MFMA t-loop: all operands already resident ----
            f32x4 binit = {b1q.x, b1q.y, b1q.z, b1q.w};
            f32x4 acc[4] = {binit, binit, binit, binit};
            #pragma unroll
            for (int t = 0; t < 4; ++t) {
                #pragma unroll
                for (int mt = 0; mt < 4; ++mt)
                    acc[mt] = __builtin_amdgcn_mfma_f32_16x16x32_f16(wcur[t], xh[t][mt], acc[mt], 0, 0, 0);
            }

            // epilogue: D[hid=quad*4+r][s=mt*16+col]; hid-reduce = 3 adds + 2 shfls
            float score01[4];
            #pragma unroll
            for (int mt = 0; mt < 4; ++mt) {
                const f32x4 a = acc[mt];
                const float pa = par[mt], ga = gp[mt];
                float ts = 0.0f;
                #pragma unroll
                for (int r = 0; r < 4; ++r) {
                    const float wpr = (r == 0) ? wpq.x : (r == 1) ? wpq.y : (r == 2) ? wpq.z : wpq.w;
                    const float wgr = (r == 0) ? wgq.x : (r == 1) ? wgq.y : (r == 2) ? wgq.z : wgq.w;
                    const float w2r = (r == 0) ? w2q.x : (r == 1) ? w2q.y : (r == 2) ? w2q.z : w2q.w;
                    const float h = fmaf(pa, wpr, fmaf(ga, wgr, a[r]));
                    ts = fmaf(fmaxf(h, 0.0f), w2r, ts);
                }
                ts += __shfl_xor(ts, 16);
                ts += __shfl_xor(ts, 32);
                score01[mt] = ts;
            }
            const float sa = (quad & 1) ? score01[1] : score01[0];
            const float sb = (quad & 1) ? score01[3] : score01[2];
            const float sv = ((quad & 2) ? sb : sa) + b2v;

            scW[nl][l] = sv;
            const float p = 1.0f / (1.0f + __expf(-sv));
            pp[slot][l]        = ppar * p;
            pp[slot + half][l] = ppar * (1.0f - p);

            #pragma unroll
            for (int t = 0; t < 4; ++t) wcur[t] = wnext[t];
        }
        __syncthreads();
    }

    // ---------------- depth 7: fold leaf mixture, accumulate in VGPRs ----------------
    float oacc[NC];
    #pragma unroll
    for (int c = 0; c < NC; ++c) oacc[c] = 0.0f;
    {
        float (*scP)[TS]  = (float(*)[TS])&scbuf[wbase[0]][0];   // d=6 scores
        float (*scP2)[TS] = (float(*)[TS])&scbuf[wbase[2]][0];   // d=5 scores

        for (int nl = wv; nl < 128; nl += 4) {
            const int n = 127 + nl;
            const int nn = (nl + 4 < 128) ? (n + 4) : 254;   // dummy refetch at end

            f16x8 wnext[4];
            {
                const f16x8* wnp = wfrag + (size_t)nn * 256 + l;
                #pragma unroll
                for (int t = 0; t < 4; ++t) wnext[t] = wnp[t * 64];
            }

            const float4 b1q = ((const float4*)(b1 + n * 16))[quad];
            const float4 w2q = ((const float4*)(w2 + n * 16))[quad];
            const float4 wpq = ((const float4*)(W1 + (size_t)n * EFF + 128 * 16))[quad];
            const float4 wgq = ((const float4*)(W1 + (size_t)n * EFF + 129 * 16))[quad];
            const float  b2v = b2[n];
            const float  ppar = pp[nl][l];
            float par[4], gp[4];
            #pragma unroll
            for (int mt = 0; mt < 4; ++mt) {
                const int scol = mt * 16 + col;
                par[mt] = scP[nl >> 1][scol];
                gp[mt]  = scP2[nl >> 2][scol];
            }

            f32x4 binit = {b1q.x, b1q.y, b1q.z, b1q.w};
            f32x4 acc[4] = {binit, binit, binit, binit};
            #pragma unroll
            for (int t = 0; t < 4; ++t) {
                #pragma unroll
                for (int mt = 0; mt < 4; ++mt)
                    acc[mt] = __builtin_amdgcn_mfma_f32_16x16x32_f16(wcur[t], xh[t][mt], acc[mt], 0, 0, 0);
            }

            float score01[4];
            #pragma unroll
            for (int mt = 0; mt < 4; ++mt) {
                const f32x4 a = acc[mt];
                const float pa = par[mt], ga = gp[mt];
                float ts = 0.0f;
                #pragma unroll
                for (int r = 0; r < 4; ++r) {
                    const float wpr = (r == 0) ? wpq.x : (r == 1) ? wpq.y : (r == 2) ? wpq.z : wpq.w;
                    const float wgr = (r == 0) ? wgq.x : (r == 1) ? wgq.y : (r == 2) ? wgq.z : wgq.w;
                    const float w2r = (r == 0) ? w2q.x : (r == 1) ? w2q.y : (r == 2) ? w2q.z : w2q.w;
                    const float h = fmaf(pa, wpr, fmaf(ga, wgr, a[r]));
                    ts = fmaf(fmaxf(h, 0.0f), w2r, ts);
                }
                ts += __shfl_xor(ts, 16);
                ts += __shfl_xor(ts, 32);
                score01[mt] = ts;
            }
            const float sa = (quad & 1) ? score01[1] : score01[0];
            const float sb = (quad & 1) ? score01[3] : score01[2];
            const float sv = ((quad & 2) ? sb : sa) + b2v;

            const float p = 1.0f / (1.0f + __expf(-sv));
            const float pL = ppar * p;
            const float pR = ppar * (1.0f - p);
            const float* llp = leaf_logits + (size_t)(2 * nl) * NC;
            #pragma unroll
            for (int c = 0; c < NC; ++c)
                oacc[c] = fmaf(pL, llp[c], fmaf(pR, llp[NC + c], oacc[c]));

            #pragma unroll
            for (int t = 0; t < 4; ++t) wcur[t] = wnext[t];
        }
    }

    // ---------------- cross-wave out reduction through scbuf ----------------
    __syncthreads();
    {
        float* red = &scbuf[0][0];         // 4*64*10 = 2560 floats <= 7168
        #pragma unroll
        for (int c = 0; c < NC; ++c)
            red[(wv * 64 + l) * NC + c] = oacc[c];
    }
    __syncthreads();
    {
        const float* red = &scbuf[0][0];
        for (int i = tid; i < TS * NC; i += BLOCK) {
            float v = red[i] + red[640 + i] + red[1280 + i] + red[1920 + i];
            out[(size_t)s0 * NC + i] = v;
        }
    }
}

} // namespace

extern "C" void kernel_launch(void* const* d_in, const int* in_sizes, int n_in,
                              void* d_out, int out_size, void* d_ws, size_t ws_size,
                              hipStream_t stream) {
    const float* x           = (const float*)d_in[0];
    const float* path_prob   = (const float*)d_in[1];
    const float* W1          = (const float*)d_in[2];
    const float* b1          = (const float*)d_in[3];
    const float* w2          = (const float*)d_in[4];
    const float* b2          = (const float*)d_in[5];
    const float* leaf_logits = (const float*)d_in[6];
    float* out = (float*)d_out;

    const int batch = in_sizes[0] / IN_DIM;                // 32768
    f16x8* wfrag = (f16x8*)d_ws;                           // 255*4*64*16B ~= 1.04 MB

    hipLaunchKernelGGL(prep_w1, dim3(NODES), dim3(256), 0, stream, W1, wfrag);
    hipLaunchKernelGGL(tree_mfma, dim3(batch / TS), dim3(BLOCK), 0, stream,
                       x, path_prob, W1, b1, w2, b2, leaf_logits, wfrag, out);
}